// Round 1
// 137.684 us; speedup vs baseline: 1.0387x; 1.0387x over previous
//
#include <hip/hip_runtime.h>
#include <hip/hip_bf16.h>

#define B_ 8
#define N_ 256
#define H_ 128
#define E_ 32
#define XLS_STRIDE 264   // bf16 elems/row: 256 + 8 pad (528 B, 8B-aligned rows)

typedef __bf16 bf16x8 __attribute__((ext_vector_type(8)));
typedef __bf16 bf16x4 __attribute__((ext_vector_type(4)));
typedef float f32x4 __attribute__((ext_vector_type(4)));

// fp32 -> bf16, RNE. Native cast: on gfx950 clang lowers fptrunc-to-bf16 via
// v_cvt_pk_bf16_f32 (m240: scalar cast beat hand-written asm/integer RNE).
// Replaces the previous 4-VALU-op integer round sequence (~110 instrs/chunk
// in agg's A-fragment build -> ~8-16).
static __device__ __forceinline__ __bf16 f2bf(float f) {
    return (__bf16)f;
}

// ws layout (W1T/W2T dropped in r12 — mlp now reads native W1/W2 coalesced):
//   xbT  : bf16, elem [0, 262144)            = bytes [0, 524288)
//   Webf : bf16, float-offset 196608, 4096 elems (8 KiB)
#define WEBF_OFF 196608

// Prep: (a) xbT[b,h,j] = bf16(x[b,j,h] + be[h]),
//       (b) We packed as per-lane bf16 MFMA B-fragments.
// r12: weight transposes removed (mlp reads W1/W2 in native layout).
__global__ __launch_bounds__(256) void prep_kernel(
    const float* __restrict__ x, const float* __restrict__ be,
    const float* __restrict__ We, float* __restrict__ ws)
{
    const int blk = blockIdx.x;
    if (blk == 256) {               // (b) We fragments: [quad][h][kk] bf16
        __bf16* Webf = (__bf16*)(ws + WEBF_OFF);
        for (int q = threadIdx.x; q < 512; q += 256) {
            const int quad = q >> 7, h = q & 127;
            bf16x8 t;
#pragma unroll
            for (int kk = 0; kk < 8; ++kk)
                t[kk] = f2bf(We[(quad * 8 + kk) * H_ + h]);
            *(bf16x8*)&Webf[q * 8] = t;
        }
        return;
    }
    // (a) per-batch x transpose, bf16 out
    __shared__ float tile[32][33];
    const int tx = threadIdx.x & 31, ty = threadIdx.x >> 5;   // ty 0..7
    const int b = blk >> 5, t = blk & 31;
    const float* src = x + (size_t)b * N_ * H_;
    __bf16* dst = (__bf16*)ws + (size_t)b * H_ * N_;
    const int r0 = (t >> 2) * 32, c0 = (t & 3) * 32;          // j0, h0
#pragma unroll
    for (int p = 0; p < 4; ++p)
        tile[ty + p * 8][tx] =
            src[(size_t)(r0 + ty + p * 8) * H_ + c0 + tx] + be[c0 + tx];
    __syncthreads();
#pragma unroll
    for (int p = 0; p < 4; ++p)
        dst[(size_t)(c0 + ty + p * 8) * N_ + r0 + tx] = f2bf(tile[tx][ty + p * 8]);
}

// Aggregation: one WG per (b,i)  ((256,2): only spill-free config).
//   h[b,i,:] = x[b,i,:] + sum_j adj*relu(xb[b,j,:] + e[b,i,j,:]@We)
// r11: xbT[b] staged to LDS (padded rows), e/adj prefetch depth 2.
// r12: f2bf -> native v_cvt_pk_bf16_f32 path (~400 fewer VALU instrs/wave;
// epilogue VALU was at parity with the 11us HBM floor, so exposed).
__global__ __launch_bounds__(256, 2) void agg_kernel(
    const int* __restrict__ adj, const float* __restrict__ e,
    const float* __restrict__ ws, const float* __restrict__ x,
    float* __restrict__ hout)
{
    __shared__ __bf16 xls[H_ * XLS_STRIDE];   // 66 KB staged xbT[b]
    __shared__ float red[4][128];
    const int bi   = blockIdx.x;      // b*256 + i
    const int b    = bi >> 8;
    const int tid  = threadIdx.x;
    const int w    = tid >> 6;
    const int lane = tid & 63;
    const int quad = lane >> 4;
    const int col  = lane & 15;

    const size_t ebase   = (size_t)bi * (N_ * E_);
    const size_t adjbase = (size_t)bi * N_;

    // (1) Depth-2 e/adj prefetch: issue the two HBM chunks FIRST so their
    // ~900cyc latency elapses during the LDS staging below.
    float4 a0v[2], a1v[2];
    int4   avv[2];
#pragma unroll
    for (int p = 0; p < 2; ++p) {
        const int j0 = (p * 4 + w) * 16;
        const float* ap = e + ebase + (size_t)(j0 + col) * E_ + quad * 8;
        a0v[p] = *(const float4*)ap;
        a1v[p] = *(const float4*)(ap + 4);
        avv[p] = *(const int4*)(adj + adjbase + j0 + quad * 4);
    }

    // (2) Stage xbT[b] (128 x 256 bf16) -> LDS, padded rows (264 bf16).
    {
        const __bf16* gx = (const __bf16*)ws + (size_t)b * (H_ * N_);
#pragma unroll 4
        for (int it = 0; it < 16; ++it) {
            const int k   = it * 256 + tid;       // 16B-chunk index
            const int row = k >> 5, cc = k & 31;
            const f32x4 v = *(const f32x4*)(gx + (size_t)row * 256 + cc * 8);
            *(f32x4*)&xls[row * XLS_STRIDE + cc * 8] = v;
        }
    }

    // (3) We B-fragments: 8 x dwordx4 from the pre-packed table (L2-hot).
    const __bf16* Webf = (const __bf16*)(ws + WEBF_OFF);
    bf16x8 bw[8];
#pragma unroll
    for (int ht = 0; ht < 8; ++ht)
        bw[ht] = *(const bf16x8*)&Webf[(quad * 128 + ht * 16 + col) * 8];

    float psum[8];
#pragma unroll
    for (int ht = 0; ht < 8; ++ht) psum[ht] = 0.0f;

    const f32x4 zero4 = {0.0f, 0.0f, 0.0f, 0.0f};

    __syncthreads();   // xls staging complete (also drains stage loads)

#pragma unroll
    for (int c = 0; c < 4; ++c) {
        const int s  = c & 1;
        const int jr = (c * 4 + w) * 16 + quad * 4;

        bf16x8 af;
        af[0] = f2bf(a0v[s].x); af[1] = f2bf(a0v[s].y);
        af[2] = f2bf(a0v[s].z); af[3] = f2bf(a0v[s].w);
        af[4] = f2bf(a1v[s].x); af[5] = f2bf(a1v[s].y);
        af[6] = f2bf(a1v[s].z); af[7] = f2bf(a1v[s].w);
        float adjf[4];
        adjf[0] = avv[s].x ? 1.0f : 0.0f;
        adjf[1] = avv[s].y ? 1.0f : 0.0f;
        adjf[2] = avv[s].z ? 1.0f : 0.0f;
        adjf[3] = avv[s].w ? 1.0f : 0.0f;

        // Refill this slot with chunk c+2 (stays 2 chunks ahead of use).
        if (c < 2) {
            const int j0n = ((c + 2) * 4 + w) * 16;
            const float* apn = e + ebase + (size_t)(j0n + col) * E_ + quad * 8;
            a0v[s] = *(const float4*)apn;
            a1v[s] = *(const float4*)(apn + 4);
            avv[s] = *(const int4*)(adj + adjbase + j0n + quad * 4);
        }

        // MFMA + epilogue; xv from LDS (ds_read_b64, ~4-way alias max).
#pragma unroll
        for (int g = 0; g < 2; ++g) {
            f32x4 acc[4];
#pragma unroll
            for (int t = 0; t < 4; ++t)
                acc[t] = __builtin_amdgcn_mfma_f32_16x16x32_bf16(af, bw[g * 4 + t], zero4, 0, 0, 0);
#pragma unroll
            for (int t = 0; t < 4; ++t) {
                const int ht = g * 4 + t;
                const bf16x4 xv = *(const bf16x4*)&xls[(ht * 16 + col) * XLS_STRIDE + jr];
#pragma unroll
                for (int r = 0; r < 4; ++r)
                    psum[ht] += adjf[r] * fmaxf(acc[t][r] + (float)xv[r], 0.0f);
            }
        }
    }

    // Quad reduce in-register, wave reduce via LDS; h = agg + x[b,i,:].
#pragma unroll
    for (int ht = 0; ht < 8; ++ht) {
        float v = psum[ht];
        v += __shfl_xor(v, 16);
        v += __shfl_xor(v, 32);
        if (lane < 16) red[w][ht * 16 + lane] = v;
    }
    __syncthreads();
    if (tid < 128) {
        const float aggv = red[0][tid] + red[1][tid] + red[2][tid] + red[3][tid];
        hout[(size_t)bi * H_ + tid] = aggv + x[(size_t)bi * H_ + tid];
    }
}

// MLP: out = relu(h@W1+b1)@W2 + b2, fp32, 8 rows/WG x 256 WGs.
// r12 rewrite: 512 threads (2 waves/SIMD, was 1 — no latency hiding), and
// weights read in NATIVE layout with per-k scalar loads: lane index = output
// column -> every global_load_dword is a coalesced 256B wave access with
// constant 1KB strides (4 loads share one address calc via imm offsets).
// The old W1T f32x4 reads were 1KB-strided per lane (~8x L2 line overfetch,
// 64KB live L1 lines vs 32KB L1). k is split 2-way (L1) / 4-way (L2) across
// the extra waves; partials combined through LDS.
__global__ __launch_bounds__(512) void mlp_kernel(
    const float* __restrict__ W1, const float* __restrict__ b1,
    const float* __restrict__ W2, const float* __restrict__ b2,
    float* __restrict__ hio)
{
    __shared__ float hs[8][128];      // 4 KB
    __shared__ float ts[8][256];      // 8 KB
    __shared__ float part[4096];      // 16 KB, reused L1 [8][2][256] / L2 [8][4][128]
    const int tid = threadIdx.x;
    const int r0  = blockIdx.x * 8;

    if (tid < 256)
        ((f32x4*)hs)[tid] = ((const f32x4*)(hio + (size_t)r0 * H_))[tid];
    __syncthreads();

    // Layer 1: thread owns (col c1, k-half kh); W1 native [128][256].
    {
        const int c1 = tid & 255, kh = tid >> 8;        // kh 0..1
        const float* wp = W1 + (size_t)(kh * 64) * 256 + c1;
        float acc[8] = {0.f, 0.f, 0.f, 0.f, 0.f, 0.f, 0.f, 0.f};
#pragma unroll 4
        for (int k = 0; k < 64; k += 4) {
            const float w0 = wp[(k + 0) * 256];
            const float w1 = wp[(k + 1) * 256];
            const float w2 = wp[(k + 2) * 256];
            const float w3 = wp[(k + 3) * 256];
#pragma unroll
            for (int r = 0; r < 8; ++r) {
                const f32x4 hv = *(const f32x4*)&hs[r][kh * 64 + k];  // LDS bcast
                acc[r] += hv[0] * w0 + hv[1] * w1 + hv[2] * w2 + hv[3] * w3;
            }
        }
#pragma unroll
        for (int r = 0; r < 8; ++r) part[(r * 2 + kh) * 256 + c1] = acc[r];
    }
    __syncthreads();
    // combine halves + bias + relu -> ts
#pragma unroll
    for (int idx = tid; idx < 2048; idx += 512) {
        const int r = idx >> 8, c = idx & 255;
        ts[r][c] = fmaxf(part[(r * 2 + 0) * 256 + c] + part[(r * 2 + 1) * 256 + c]
                         + b1[c], 0.0f);
    }
    __syncthreads();

    // Layer 2: thread owns (col c2, k-quarter kq); W2 native [256][128].
    {
        const int c2 = tid & 127, kq = tid >> 7;        // kq 0..3
        const float* wp = W2 + (size_t)(kq * 64) * 128 + c2;
        float acc[8] = {0.f, 0.f, 0.f, 0.f, 0.f, 0.f, 0.f, 0.f};
#pragma unroll 4
        for (int k = 0; k < 64; k += 4) {
            const float w0 = wp[(k + 0) * 128];
            const float w1 = wp[(k + 1) * 128];
            const float w2 = wp[(k + 2) * 128];
            const float w3 = wp[(k + 3) * 128];
#pragma unroll
            for (int r = 0; r < 8; ++r) {
                const f32x4 tv = *(const f32x4*)&ts[r][kq * 64 + k];  // LDS bcast
                acc[r] += tv[0] * w0 + tv[1] * w1 + tv[2] * w2 + tv[3] * w3;
            }
        }
#pragma unroll
        for (int r = 0; r < 8; ++r) part[(r * 4 + kq) * 128 + c2] = acc[r];
    }
    __syncthreads();
#pragma unroll
    for (int idx = tid; idx < 1024; idx += 512) {
        const int r = idx >> 7, c = idx & 127;
        hio[(size_t)(r0 + r) * H_ + c] =
            part[(r * 4 + 0) * 128 + c] + part[(r * 4 + 1) * 128 + c] +
            part[(r * 4 + 2) * 128 + c] + part[(r * 4 + 3) * 128 + c] + b2[c];
    }
}

extern "C" void kernel_launch(void* const* d_in, const int* in_sizes, int n_in,
                              void* d_out, int out_size, void* d_ws, size_t ws_size,
                              hipStream_t stream) {
    const float* x   = (const float*)d_in[0];
    const int*   adj = (const int*)  d_in[1];
    const float* e   = (const float*)d_in[2];
    const float* We  = (const float*)d_in[3];
    const float* be  = (const float*)d_in[4];
    const float* W1  = (const float*)d_in[5];
    const float* b1  = (const float*)d_in[6];
    const float* W2  = (const float*)d_in[7];
    const float* b2  = (const float*)d_in[8];
    float* out = (float*)d_out;
    float* ws  = (float*)d_ws;   // xbT bf16 (512 KiB) + Webf (8 KiB)

    prep_kernel<<<dim3(257), dim3(256), 0, stream>>>(x, be, We, ws);
    agg_kernel<<<dim3(B_ * N_), dim3(256), 0, stream>>>(adj, e, ws, x, out);
    mlp_kernel<<<dim3(B_ * N_ / 8), dim3(512), 0, stream>>>(W1, b1, W2, b2, out);
}